// Round 12
// baseline (508.014 us; speedup 1.0000x reference)
//
#include <hip/hip_runtime.h>

typedef float     v2f __attribute__((ext_vector_type(2)));
typedef _Float16  v2h __attribute__((ext_vector_type(2)));
typedef unsigned int uint;

#define BB 2048
#define NBLK (BB / 2)             // 2 batches per wave
#define TT 1024
#define CC 9
#define HH 36
#define CSTEPS 32                 // timesteps per x-chunk
#define CF (CSTEPS * CC)          // 288 f32 per chunk per batch
#define FPAD 320                  // linear staging size per batch (5 x 64)
#define XP 12                     // padded f32 per step (48 B, 16B-aligned)
#define NCH (TT / CSTEPS)         // 32 chunks

// Compiler-level ordering fence for same-wave LDS write->read handoffs
// (R7/R8 lesson: TBAA no-alias between differently-typed LDS puns lets the
// scheduler hoist reads above same-step writes -> stale recurrence).
__device__ __forceinline__ void lds_fence() {
    asm volatile("" ::: "memory");
    __builtin_amdgcn_sched_barrier(0);
}

__device__ __forceinline__ void pinh(v2h& v) {
    uint t = __builtin_bit_cast(uint, v);
    asm volatile("" : "+v"(t));
    v = __builtin_bit_cast(v2h, t);
}
__device__ __forceinline__ void pin2f(v2f& v) {
    uint64_t t = __builtin_bit_cast(uint64_t, v);
    asm volatile("" : "+v"(t));
    v = __builtin_bit_cast(v2f, t);
}

// async global->LDS, 4 B per lane (LDS dest = base + lane*4; global src per-lane)
__device__ __forceinline__ void gload4(const float* g, float* l) {
    __builtin_amdgcn_global_load_lds(
        (const __attribute__((address_space(1))) unsigned int*)g,
        (__attribute__((address_space(3))) unsigned int*)l,
        4, 0, 0);
}

// TWO batch elements per wave (intra-wave ILP attacks the per-step latency
// floor R6/R9/R10 all hit at ~960 cy/step: fdot2 dep chain + trans chain +
// LDS broadcast roundtrip can't be hidden by 2 waves/SIMD). Lane j owns
// hidden unit j for BOTH batches (weights are batch-invariant: one pinned
// set serves both chains). Unit-per-lane => only ONE LDS roundtrip per step
// (h broadcast); x-dots f32 in-loop (h-independent, fill stall slots).
// waves_per_eu(1,1): 1 wave/SIMD, full 512-VGPR budget -> no AGPR parking.
__global__ __launch_bounds__(64)
__attribute__((amdgpu_waves_per_eu(1, 1)))
void gru_kernel(
    const float* __restrict__ x,      // (B,T,C)
    const float* __restrict__ w_ih,   // (3H,C)
    const float* __restrict__ w_hh,   // (3H,H)
    const float* __restrict__ b_ih,   // (3H)
    const float* __restrict__ b_hh,   // (3H)
    const float* __restrict__ w_head, // (1,H)
    const float* __restrict__ b_head, // (1)
    float* __restrict__ out)          // (B,1)
{
    const int bid = blockIdx.x;
    const int l   = threadIdx.x;
    const int b0  = 2 * bid;
    const int b1  = 2 * bid + 1;

    __shared__ __align__(16) float    fstage[2][FPAD];        // gload dest (linear)
    __shared__ __align__(16) float    xpad[2][CSTEPS * XP];   // padded x per step
    __shared__ __align__(16) _Float16 hbuf[2][40];            // h broadcast (36+pad)

    const int u = (l < HH) ? l : HH - 1;   // owned hidden unit (lanes>=36 shadow 35)

    // ---- pinned per-lane weights: w_hh fp16 (RTE), w_ih f32, biases ----
    v2h whr[18], whz[18], whn[18];
    v2f wir[4], wiz[4], win[4];
    float wir8, wiz8, win8;
    float bxr, bxz, bxn, bnh;
    {
        const float* pr = w_hh + (size_t)u * HH;
        const float* pz = w_hh + (size_t)(HH + u) * HH;
        const float* pn = w_hh + (size_t)(2 * HH + u) * HH;
#pragma unroll
        for (int k = 0; k < 18; ++k) {
            whr[k] = (v2h){(_Float16)pr[2*k], (_Float16)pr[2*k+1]};
            whz[k] = (v2h){(_Float16)pz[2*k], (_Float16)pz[2*k+1]};
            whn[k] = (v2h){(_Float16)pn[2*k], (_Float16)pn[2*k+1]};
        }
        const float* qr = w_ih + (size_t)u * CC;
        const float* qz = w_ih + (size_t)(HH + u) * CC;
        const float* qn = w_ih + (size_t)(2 * HH + u) * CC;
#pragma unroll
        for (int p = 0; p < 4; ++p) {
            wir[p] = (v2f){qr[2*p], qr[2*p+1]};
            wiz[p] = (v2f){qz[2*p], qz[2*p+1]};
            win[p] = (v2f){qn[2*p], qn[2*p+1]};
        }
        wir8 = qr[8]; wiz8 = qz[8]; win8 = qn[8];
        bxr = b_ih[u] + b_hh[u];
        bxz = b_ih[HH + u] + b_hh[HH + u];
        bxn = b_ih[2 * HH + u];
        bnh = b_hh[2 * HH + u];
    }
#pragma unroll
    for (int k = 0; k < 18; ++k) { pinh(whr[k]); pinh(whz[k]); pinh(whn[k]); }
#pragma unroll
    for (int p = 0; p < 4; ++p) { pin2f(wir[p]); pin2f(wiz[p]); pin2f(win[p]); }
    asm volatile("" : "+v"(wir8), "+v"(wiz8), "+v"(win8));
    asm volatile("" : "+v"(bxr), "+v"(bxz), "+v"(bxn), "+v"(bnh));

    // staging offsets: dest fstage[b][k*64+l] <- x[b-base + clamp(k*64+l)]
    int offs[5];
#pragma unroll
    for (int k = 0; k < 5; ++k) {
        int idx = k * 64 + l;
        offs[k] = (idx < CF) ? idx : (CF - 1);
    }

    const float* xg0 = x + (size_t)b0 * (TT * CC);
    const float* xg1 = x + (size_t)b1 * (TT * CC);

    // prefetch chunk 0
#pragma unroll
    for (int k = 0; k < 5; ++k) {
        gload4(xg0 + offs[k], &fstage[0][k * 64]);
        gload4(xg1 + offs[k], &fstage[1][k * 64]);
    }

    v2h h2A[18], h2B[18];
#pragma unroll
    for (int k = 0; k < 18; ++k) {
        h2A[k] = (v2h){(_Float16)0.f, (_Float16)0.f};
        h2B[k] = (v2h){(_Float16)0.f, (_Float16)0.f};
    }
    float hA = 0.f, hB = 0.f;

    for (int c = 0; c < NCH; ++c) {
        asm volatile("s_waitcnt vmcnt(0)" ::: "memory");
        __builtin_amdgcn_sched_barrier(0);

        // ---- restage to padded layout: lanes 0..31 batch0 step l,
        //      lanes 32..63 batch1 step l-32 ----
        {
            const int bs = l >> 5;
            const int s  = l & 31;
            const float* src = &fstage[bs][s * CC];
            float xf[9];
#pragma unroll
            for (int q = 0; q < 9; ++q) xf[q] = src[q];
            float* dst = &xpad[bs][s * XP];
            *(float4*)dst       = (float4){xf[0], xf[1], xf[2], xf[3]};
            *(float4*)(dst + 4) = (float4){xf[4], xf[5], xf[6], xf[7]};
            dst[8] = xf[8];
        }
        lds_fence();   // xpad writes -> step reads

        // ---- issue next chunk's gloads (in flight across 32 steps) ----
        if (c + 1 < NCH) {
            const float* s0 = xg0 + (size_t)(c + 1) * CF;
            const float* s1 = xg1 + (size_t)(c + 1) * CF;
#pragma unroll
            for (int k = 0; k < 5; ++k) {
                gload4(s0 + offs[k], &fstage[0][k * 64]);
                gload4(s1 + offs[k], &fstage[1][k * 64]);
            }
        }

        for (int s = 0; s < CSTEPS; ++s) {
            // x_t for both batches (uniform-address aligned reads)
            const float* xA = &xpad[0][s * XP];
            const float* xB = &xpad[1][s * XP];
            float4 a03 = *(const float4*)xA;
            float4 a47 = *(const float4*)(xA + 4);
            float  a8  = xA[8];
            float4 c03 = *(const float4*)xB;
            float4 c47 = *(const float4*)(xB + 4);
            float  c8  = xB[8];
            v2f XA0 = (v2f){a03.x, a03.y}, XA1 = (v2f){a03.z, a03.w};
            v2f XA2 = (v2f){a47.x, a47.y}, XA3 = (v2f){a47.z, a47.w};
            v2f XB0 = (v2f){c03.x, c03.y}, XB1 = (v2f){c03.z, c03.w};
            v2f XB2 = (v2f){c47.x, c47.y}, XB3 = (v2f){c47.z, c47.w};

            // x-dots, f32 (6 independent pk_fma chains)
            v2f tra = (v2f){bxr, 0.f}, tza = (v2f){bxz, 0.f}, tna = (v2f){bxn, 0.f};
            v2f trb = (v2f){bxr, 0.f}, tzb = (v2f){bxz, 0.f}, tnb = (v2f){bxn, 0.f};
            tra = __builtin_elementwise_fma(wir[0], XA0, tra);
            tza = __builtin_elementwise_fma(wiz[0], XA0, tza);
            tna = __builtin_elementwise_fma(win[0], XA0, tna);
            trb = __builtin_elementwise_fma(wir[0], XB0, trb);
            tzb = __builtin_elementwise_fma(wiz[0], XB0, tzb);
            tnb = __builtin_elementwise_fma(win[0], XB0, tnb);
            tra = __builtin_elementwise_fma(wir[1], XA1, tra);
            tza = __builtin_elementwise_fma(wiz[1], XA1, tza);
            tna = __builtin_elementwise_fma(win[1], XA1, tna);
            trb = __builtin_elementwise_fma(wir[1], XB1, trb);
            tzb = __builtin_elementwise_fma(wiz[1], XB1, tzb);
            tnb = __builtin_elementwise_fma(win[1], XB1, tnb);
            tra = __builtin_elementwise_fma(wir[2], XA2, tra);
            tza = __builtin_elementwise_fma(wiz[2], XA2, tza);
            tna = __builtin_elementwise_fma(win[2], XA2, tna);
            trb = __builtin_elementwise_fma(wir[2], XB2, trb);
            tzb = __builtin_elementwise_fma(wiz[2], XB2, tzb);
            tnb = __builtin_elementwise_fma(win[2], XB2, tnb);
            tra = __builtin_elementwise_fma(wir[3], XA3, tra);
            tza = __builtin_elementwise_fma(wiz[3], XA3, tza);
            tna = __builtin_elementwise_fma(win[3], XA3, tna);
            trb = __builtin_elementwise_fma(wir[3], XB3, trb);
            tzb = __builtin_elementwise_fma(wiz[3], XB3, tzb);
            tnb = __builtin_elementwise_fma(win[3], XB3, tnb);
            float gxrA = fmaf(wir8, a8, tra.x + tra.y);
            float gxzA = fmaf(wiz8, a8, tza.x + tza.y);
            float gxnA = fmaf(win8, a8, tna.x + tna.y);
            float gxrB = fmaf(wir8, c8, trb.x + trb.y);
            float gxzB = fmaf(wiz8, c8, tzb.x + tzb.y);
            float gxnB = fmaf(win8, c8, tnb.x + tnb.y);

            // h-dots: 6 independent fdot2 chains (A/B x r/z/n)
            float ahrA = 0.f, ahzA = 0.f, ahnA = bnh;
            float ahrB = 0.f, ahzB = 0.f, ahnB = bnh;
#pragma unroll
            for (int k = 0; k < 18; ++k) {
                ahrA = __builtin_amdgcn_fdot2(whr[k], h2A[k], ahrA, false);
                ahzA = __builtin_amdgcn_fdot2(whz[k], h2A[k], ahzA, false);
                ahnA = __builtin_amdgcn_fdot2(whn[k], h2A[k], ahnA, false);
                ahrB = __builtin_amdgcn_fdot2(whr[k], h2B[k], ahrB, false);
                ahzB = __builtin_amdgcn_fdot2(whz[k], h2B[k], ahzB, false);
                ahnB = __builtin_amdgcn_fdot2(whn[k], h2B[k], ahnB, false);
            }

            // activations (all lanes; garbage on l>=36 never escapes)
            float srA = gxrA + ahrA, szA = gxzA + ahzA;
            float rA = __builtin_amdgcn_rcpf(1.f + __expf(-srA));
            float zA = __builtin_amdgcn_rcpf(1.f + __expf(-szA));
            float aA = gxnA + rA * ahnA;
            float nA = 1.f - 2.f * __builtin_amdgcn_rcpf(__expf(2.f * aA) + 1.f);
            hA = zA * (hA - nA) + nA;

            float srB = gxrB + ahrB, szB = gxzB + ahzB;
            float rB = __builtin_amdgcn_rcpf(1.f + __expf(-srB));
            float zB = __builtin_amdgcn_rcpf(1.f + __expf(-szB));
            float aB = gxnB + rB * ahnB;
            float nB = 1.f - 2.f * __builtin_amdgcn_rcpf(__expf(2.f * aB) + 1.f);
            hB = zB * (hB - nB) + nB;

            if (l < HH) {
                hbuf[0][l] = (_Float16)hA;   // RTE
                hbuf[1][l] = (_Float16)hB;
            }
            lds_fence();   // hbuf writes -> h2 reads

            // broadcast both h states (uniform-address reads)
#pragma unroll
            for (int q = 0; q < 4; ++q) {
                uint4 t4 = ((const uint4*)hbuf[0])[q];
                h2A[4*q+0] = __builtin_bit_cast(v2h, t4.x);
                h2A[4*q+1] = __builtin_bit_cast(v2h, t4.y);
                h2A[4*q+2] = __builtin_bit_cast(v2h, t4.z);
                h2A[4*q+3] = __builtin_bit_cast(v2h, t4.w);
                uint4 u4 = ((const uint4*)hbuf[1])[q];
                h2B[4*q+0] = __builtin_bit_cast(v2h, u4.x);
                h2B[4*q+1] = __builtin_bit_cast(v2h, u4.y);
                h2B[4*q+2] = __builtin_bit_cast(v2h, u4.z);
                h2B[4*q+3] = __builtin_bit_cast(v2h, u4.w);
            }
            {
                uint2 t2 = ((const uint2*)hbuf[0])[8];
                h2A[16] = __builtin_bit_cast(v2h, t2.x);
                h2A[17] = __builtin_bit_cast(v2h, t2.y);
                uint2 u2 = ((const uint2*)hbuf[1])[8];
                h2B[16] = __builtin_bit_cast(v2h, u2.x);
                h2B[17] = __builtin_bit_cast(v2h, u2.y);
            }
        }
    }

    // head: out[b] = sum_j h[j] * w_head[j] + b_head (both batches)
    float whead = (l < HH) ? w_head[l] : 0.f;
    float vA = (l < HH) ? hA * whead : 0.f;
    float vB = (l < HH) ? hB * whead : 0.f;
#pragma unroll
    for (int off = 32; off; off >>= 1) {
        vA += __shfl_down(vA, off);
        vB += __shfl_down(vB, off);
    }
    if (l == 0) {
        out[b0] = vA + b_head[0];
        out[b1] = vB + b_head[0];
    }
}

extern "C" void kernel_launch(void* const* d_in, const int* in_sizes, int n_in,
                              void* d_out, int out_size, void* d_ws, size_t ws_size,
                              hipStream_t stream) {
    const float* x      = (const float*)d_in[0];
    const float* w_ih   = (const float*)d_in[1];
    const float* w_hh   = (const float*)d_in[2];
    const float* b_ih   = (const float*)d_in[3];
    const float* b_hh   = (const float*)d_in[4];
    const float* w_head = (const float*)d_in[5];
    const float* b_head = (const float*)d_in[6];
    float* out = (float*)d_out;

    gru_kernel<<<NBLK, 64, 0, stream>>>(x, w_ih, w_hh, b_ih, b_hh,
                                        w_head, b_head, out);
}

// Round 14
// 481.706 us; speedup vs baseline: 1.0546x; 1.0546x over previous
//
#include <hip/hip_runtime.h>

typedef float     v2f __attribute__((ext_vector_type(2)));
typedef _Float16  v2h __attribute__((ext_vector_type(2)));
typedef unsigned int uint;

#define BB 2048
#define TT 1024
#define CC 9
#define HH 36
#define G3 108
#define CSTEPS 32                 // timesteps per x-chunk
#define CF (CSTEPS * CC)          // 288 f32 per chunk
#define FPAD 320                  // linear staging floats (5 x 64)
#define GXS 112                   // f32 stride per step in gxbuf
#define NCH (TT / CSTEPS)         // 32 chunks

// chunk-boundary fence (proven R9/R10); NOT used inside the step loop
__device__ __forceinline__ void lds_fence() {
    asm volatile("" ::: "memory");
    __builtin_amdgcn_sched_barrier(0);
}

__device__ __forceinline__ void pinh(v2h& v) {
    uint t = __builtin_bit_cast(uint, v);
    asm volatile("" : "+v"(t));
    v = __builtin_bit_cast(v2h, t);
}

// async global->LDS, 4 B per lane
__device__ __forceinline__ void gload4(const float* g, float* l) {
    __builtin_amdgcn_global_load_lds(
        (const __attribute__((address_space(1))) unsigned int*)g,
        (__attribute__((address_space(3))) unsigned int*)l,
        4, 0, 0);
}

// One wave per batch. Lane j (=unit) owns all 3 gates of unit j.
// Step loop has NO LDS writes and NO fences: the h broadcast is pure
// register traffic -- mov_dpp pair-swap + 2x RTE cvt + pack + 18 v_readlane
// into SGPRs (exact, order-safe, no memory latency). h2 lives in SGPRs so
// the VGPR working set (~75) finally fits under the allocator cap (~88):
// no AGPR parking. x-parts come from R10's proven pre-pass (gx in LDS,
// chunk-boundary fence only; 3 latency-tolerant reads/step).
__global__ __launch_bounds__(64)
__attribute__((amdgpu_waves_per_eu(2, 2)))
void gru_kernel(
    const float* __restrict__ x,      // (B,T,C)
    const float* __restrict__ w_ih,   // (3H,C)
    const float* __restrict__ w_hh,   // (3H,H)
    const float* __restrict__ b_ih,   // (3H)
    const float* __restrict__ b_hh,   // (3H)
    const float* __restrict__ w_head, // (1,H)
    const float* __restrict__ b_head, // (1)
    float* __restrict__ out)          // (B,1)
{
    const int b = blockIdx.x;
    const int l = threadIdx.x;

    __shared__ __align__(16) float fstage[FPAD];          // gload dest (linear)
    __shared__ __align__(16) float gxbuf[CSTEPS * GXS];   // x-parts per step/row

    const int u = (l < HH) ? l : HH - 1;     // owned unit (lanes>=36 shadow 35)
    const int i0 = (2 * l     < G3) ? 2 * l     : G3 - 1;   // pre-pass rows
    const int i1 = (2 * l + 1 < G3) ? 2 * l + 1 : G3 - 1;

    // ---- pinned step-loop weights: w_hh fp16 (RTE) + n-gate h-bias ----
    v2h whr[18], whz[18], whn[18];
    float bnh;
    {
        const float* pr = w_hh + (size_t)u * HH;
        const float* pz = w_hh + (size_t)(HH + u) * HH;
        const float* pn = w_hh + (size_t)(2 * HH + u) * HH;
#pragma unroll
        for (int k = 0; k < 18; ++k) {
            whr[k] = (v2h){(_Float16)pr[2*k], (_Float16)pr[2*k+1]};
            whz[k] = (v2h){(_Float16)pz[2*k], (_Float16)pz[2*k+1]};
            whn[k] = (v2h){(_Float16)pn[2*k], (_Float16)pn[2*k+1]};
        }
        bnh = b_hh[2 * HH + u];
    }
#pragma unroll
    for (int k = 0; k < 18; ++k) { pinh(whr[k]); pinh(whz[k]); pinh(whn[k]); }
    asm volatile("" : "+v"(bnh));

    // ---- pre-pass weights (UNPINNED; live only in the pre-pass) ----
    float wxa[CC], wxb[CC], bA0, bA1;
    {
        const float* q0 = w_ih + (size_t)i0 * CC;
        const float* q1 = w_ih + (size_t)i1 * CC;
#pragma unroll
        for (int q = 0; q < CC; ++q) { wxa[q] = q0[q]; wxb[q] = q1[q]; }
        const bool n0 = i0 >= 2 * HH, n1 = i1 >= 2 * HH;
        bA0 = n0 ? b_ih[i0] : (b_ih[i0] + b_hh[i0]);
        bA1 = n1 ? b_ih[i1] : (b_ih[i1] + b_hh[i1]);
    }

    int offs[5];
#pragma unroll
    for (int k = 0; k < 5; ++k) {
        int idx = k * 64 + l;
        offs[k] = (idx < CF) ? idx : (CF - 1);
    }

    const float* xg = x + (size_t)b * (TT * CC);
#pragma unroll
    for (int k = 0; k < 5; ++k) gload4(xg + offs[k], &fstage[k * 64]);

    // h2 broadcast state: 18 uniform half2 words (SGPR-resident)
    v2h h2s[18];
#pragma unroll
    for (int k = 0; k < 18; ++k) h2s[k] = (v2h){(_Float16)0.f, (_Float16)0.f};
    float h_own = 0.f;

    for (int c = 0; c < NCH; ++c) {
        asm volatile("s_waitcnt vmcnt(0)" ::: "memory");
        __builtin_amdgcn_sched_barrier(0);

        // ---- PRE-PASS (proven, R10): gx[s][2l,2l+1] for all 32 steps ----
        for (int s = 0; s < CSTEPS; ++s) {
            const float* xs = &fstage[s * CC];   // uniform -> broadcast reads
            float a0 = bA0, a1 = bA1;
#pragma unroll
            for (int q = 0; q < CC; ++q) {
                float xv = xs[q];
                a0 = fmaf(wxa[q], xv, a0);
                a1 = fmaf(wxb[q], xv, a1);
            }
            if (l < 54) *(v2f*)&gxbuf[s * GXS + 2 * l] = (v2f){a0, a1};
        }
        lds_fence();   // gxbuf writes -> step reads; fstage reads -> restage

        // ---- issue next chunk's gloads ----
        if (c + 1 < NCH) {
            const float* src = xg + (size_t)(c + 1) * CF;
#pragma unroll
            for (int k = 0; k < 5; ++k) gload4(src + offs[k], &fstage[k * 64]);
        }

        // ---- SERIAL step loop: no LDS writes, no fences ----
#pragma unroll 2
        for (int s = 0; s < CSTEPS; ++s) {
            float gxr = gxbuf[s * GXS + u];
            float gxz = gxbuf[s * GXS + HH + u];
            float gxn = gxbuf[s * GXS + 2 * HH + u];

            // 6 half-length fdot2 chains on uniform h2s
            float r0 = 0.f, r1 = 0.f, z0 = 0.f, z1 = 0.f, n0 = bnh, n1 = 0.f;
#pragma unroll
            for (int k = 0; k < 9; ++k) {
                r0 = __builtin_amdgcn_fdot2(whr[k],     h2s[k],     r0, false);
                z0 = __builtin_amdgcn_fdot2(whz[k],     h2s[k],     z0, false);
                n0 = __builtin_amdgcn_fdot2(whn[k],     h2s[k],     n0, false);
                r1 = __builtin_amdgcn_fdot2(whr[k + 9], h2s[k + 9], r1, false);
                z1 = __builtin_amdgcn_fdot2(whz[k + 9], h2s[k + 9], z1, false);
                n1 = __builtin_amdgcn_fdot2(whn[k + 9], h2s[k + 9], n1, false);
            }
            float sr = gxr + (r0 + r1);
            float sz = gxz + (z0 + z1);
            float gh = n0 + n1;

            float r = __builtin_amdgcn_rcpf(1.f + __expf(-sr));
            float z = __builtin_amdgcn_rcpf(1.f + __expf(-sz));
            float a = gxn + r * gh;
            float n = 1.f - 2.f * __builtin_amdgcn_rcpf(__expf(2.f * a) + 1.f);
            h_own = z * (h_own - n) + n;

            // ---- register h-broadcast (exact, no memory) ----
            // neighbor h via DPP quad_perm swap (1<->0, 3<->2)
            float nb = __builtin_bit_cast(float,
                __builtin_amdgcn_mov_dpp(__builtin_bit_cast(int, h_own),
                                         0xB1, 0xF, 0xF, true));
            // RTE converts + pack: even lane 2m holds (h[2m], h[2m+1])
            uint lo = (uint)__builtin_bit_cast(unsigned short, (_Float16)h_own);
            uint hi = (uint)__builtin_bit_cast(unsigned short, (_Float16)nb);
            uint hw = lo | (hi << 16);
            // broadcast 18 words from even lanes into uniform regs
#pragma unroll
            for (int k = 0; k < 18; ++k)
                h2s[k] = __builtin_bit_cast(v2h,
                             __builtin_amdgcn_readlane(hw, 2 * k));
        }
    }

    // head: out[b] = sum_j h[j] * w_head[j] + b_head
    float whead = (l < HH) ? w_head[l] : 0.f;
    float v = (l < HH) ? h_own * whead : 0.f;
#pragma unroll
    for (int off = 32; off; off >>= 1) v += __shfl_down(v, off);
    if (l == 0) out[b] = v + b_head[0];
}

extern "C" void kernel_launch(void* const* d_in, const int* in_sizes, int n_in,
                              void* d_out, int out_size, void* d_ws, size_t ws_size,
                              hipStream_t stream) {
    const float* x      = (const float*)d_in[0];
    const float* w_ih   = (const float*)d_in[1];
    const float* w_hh   = (const float*)d_in[2];
    const float* b_ih   = (const float*)d_in[3];
    const float* b_hh   = (const float*)d_in[4];
    const float* w_head = (const float*)d_in[5];
    const float* b_head = (const float*)d_in[6];
    float* out = (float*)d_out;

    gru_kernel<<<BB, 64, 0, stream>>>(x, w_ih, w_hh, b_ih, b_hh,
                                      w_head, b_head, out);
}

// Round 15
// 402.938 us; speedup vs baseline: 1.2608x; 1.1955x over previous
//
#include <hip/hip_runtime.h>

typedef float     v2f __attribute__((ext_vector_type(2)));
typedef _Float16  v2h __attribute__((ext_vector_type(2)));
typedef unsigned int uint;

#define BB 2048
#define TT 1024
#define CC 9
#define HH 36
#define CSTEPS 64                 // timesteps per x-chunk
#define CF (CSTEPS * CC)          // 576 floats per chunk
#define NCH (TT / CSTEPS)         // 16 chunks

__device__ __forceinline__ void pin2f(v2f& v) {
    uint64_t t = __builtin_bit_cast(uint64_t, v);
    asm volatile("" : "+v"(t));
    v = __builtin_bit_cast(v2f, t);
}
__device__ __forceinline__ void pinh(v2h& v) {
    uint t = __builtin_bit_cast(uint, v);
    asm volatile("" : "+v"(t));
    v = __builtin_bit_cast(v2h, t);
}

// async global->LDS, 4 B per lane (wave writes 256 B: lds_base + lane*4)
__device__ __forceinline__ void gload4(const float* g, float* l) {
    __builtin_amdgcn_global_load_lds(
        (const __attribute__((address_space(1))) unsigned int*)g,
        (__attribute__((address_space(3))) unsigned int*)l,
        4, 0, 0);
}

// CHAMPION (R6, 403 us): one wave per batch element. Lane j < 36 owns hidden
// unit j and all 3 of its gates. h-path fp16 (v_dot2_f32_f16, f32 accum, RTE);
// x-path f32 (fp16 x failed: integrator amplification). waves_per_eu(2,2)
// pins occupancy so the allocator budget matches the 2-wave/SIMD reality.
// x staged 64 steps ahead in LDS via global_load_lds, double-use of fstage.
// Campaign summary: five structural variants (pre-pass, fences, 2-batch ILP,
// readlane broadcast) all land 403-530 us; this one is issue-bound at
// VALUBusy ~81% with HBM at ~1% -- the practical plateau for this serial
// recurrence without disasm-guided codegen surgery.
__global__ __launch_bounds__(64)
__attribute__((amdgpu_waves_per_eu(2, 2)))
void gru_kernel(
    const float* __restrict__ x,      // (B,T,C)
    const float* __restrict__ w_ih,   // (3H,C)
    const float* __restrict__ w_hh,   // (3H,H)
    const float* __restrict__ b_ih,   // (3H)
    const float* __restrict__ b_hh,   // (3H)
    const float* __restrict__ w_head, // (1,H)
    const float* __restrict__ b_head, // (1)
    float* __restrict__ out)          // (B,1)
{
    const int b = blockIdx.x;
    const int j = threadIdx.x;

    __shared__ __align__(16) _Float16 hbuf16[64];   // h bcast, 64-wide (no branch)
    __shared__ __align__(16) float xlds[2][CF];     // x chunk double buffer

    // ---- per-lane weights (lane >= 36 loads row 0; values never escape) ----
    const int jj = (j < HH) ? j : 0;
    v2h wrh[18], wzh[18], wnh[18];    // w_hh rows, fp16 pairs
    v2f wri[4], wzi[4], wni[4];       // w_ih rows, f32 pairs
    float wri8, wzi8, wni8, br, bz, bni, bnh;
    {
        const float* pr = w_hh + (size_t)jj * HH;
        const float* pz = w_hh + (size_t)(HH + jj) * HH;
        const float* pn = w_hh + (size_t)(2 * HH + jj) * HH;
#pragma unroll
        for (int k = 0; k < 18; ++k) {
            wrh[k] = (v2h){(_Float16)pr[2*k], (_Float16)pr[2*k+1]};
            wzh[k] = (v2h){(_Float16)pz[2*k], (_Float16)pz[2*k+1]};
            wnh[k] = (v2h){(_Float16)pn[2*k], (_Float16)pn[2*k+1]};
        }
        const float* qr = w_ih + (size_t)jj * CC;
        const float* qz = w_ih + (size_t)(HH + jj) * CC;
        const float* qn = w_ih + (size_t)(2 * HH + jj) * CC;
#pragma unroll
        for (int p = 0; p < 4; ++p) {
            wri[p] = (v2f){qr[2*p], qr[2*p+1]};
            wzi[p] = (v2f){qz[2*p], qz[2*p+1]};
            wni[p] = (v2f){qn[2*p], qn[2*p+1]};
        }
        wri8 = qr[8]; wzi8 = qz[8]; wni8 = qn[8];
        br  = b_ih[jj] + b_hh[jj];
        bz  = b_ih[HH + jj] + b_hh[HH + jj];
        bni = b_ih[2 * HH + jj];
        bnh = b_hh[2 * HH + jj];
    }
    // ---- pin: loads may not be sunk/rematerialized into the loop ----
#pragma unroll
    for (int k = 0; k < 18; ++k) { pinh(wrh[k]); pinh(wzh[k]); pinh(wnh[k]); }
#pragma unroll
    for (int p = 0; p < 4; ++p) { pin2f(wri[p]); pin2f(wzi[p]); pin2f(wni[p]); }
    asm volatile("" : "+v"(wri8), "+v"(wzi8), "+v"(wni8));
    asm volatile("" : "+v"(br), "+v"(bz), "+v"(bni), "+v"(bnh));

    const float* xg = x + (size_t)b * (TT * CC);

    // prefetch chunk 0
#pragma unroll
    for (int k = 0; k < 9; ++k) gload4(xg + k * 64 + j, &xlds[0][k * 64]);

    v2h h2[18];
#pragma unroll
    for (int k = 0; k < 18; ++k) h2[k] = (v2h){(_Float16)0.f, (_Float16)0.f};
    float h_own = 0.f;

    for (int c = 0; c < NCH; ++c) {
        asm volatile("s_waitcnt vmcnt(0)" ::: "memory");
        __builtin_amdgcn_sched_barrier(0);
        if (c + 1 < NCH) {
            const float* src = xg + (size_t)(c + 1) * CF;
            float* dst = &xlds[(c + 1) & 1][0];
#pragma unroll
            for (int k = 0; k < 9; ++k) gload4(src + k * 64 + j, dst + k * 64);
        }
        const float* xc = &xlds[c & 1][0];

#pragma unroll 2
        for (int s = 0; s < CSTEPS; ++s) {
            const float* xs = xc + s * CC;
            float xv[CC];
#pragma unroll
            for (int cc = 0; cc < CC; ++cc) xv[cc] = xs[cc];

            // x-part (f32): init with biases
            v2f axr = (v2f){br,  0.f};
            v2f axz = (v2f){bz,  0.f};
            v2f axn = (v2f){bni, 0.f};
#pragma unroll
            for (int p = 0; p < 4; ++p) {
                v2f xp2 = (v2f){xv[2*p], xv[2*p+1]};
                axr = __builtin_elementwise_fma(wri[p], xp2, axr);
                axz = __builtin_elementwise_fma(wzi[p], xp2, axz);
                axn = __builtin_elementwise_fma(wni[p], xp2, axn);
            }
            float sr = fmaf(wri8, xv[8], axr.x + axr.y);
            float sz = fmaf(wzi8, xv[8], axz.x + axz.y);
            float sn = fmaf(wni8, xv[8], axn.x + axn.y);
            float gn = bnh;

            // h-part: fp16 dot2 with f32 accumulation
#pragma unroll
            for (int k = 0; k < 18; ++k) {
                sr = __builtin_amdgcn_fdot2(wrh[k], h2[k], sr, false);
                sz = __builtin_amdgcn_fdot2(wzh[k], h2[k], sz, false);
                gn = __builtin_amdgcn_fdot2(wnh[k], h2[k], gn, false);
            }

            float r = __builtin_amdgcn_rcpf(1.f + __expf(-sr));
            float z = __builtin_amdgcn_rcpf(1.f + __expf(-sz));
            float a = sn + r * gn;
            float n = 1.f - 2.f * __builtin_amdgcn_rcpf(__expf(2.f * a) + 1.f);
            h_own = z * (h_own - n) + n;

            // broadcast h_t: unconditional scalar f16 write (64-wide buffer,
            // lanes >= 36 write pad), then packed reads. 1-wave block: per-wave
            // DS ordering, no barrier.
            hbuf16[j] = (_Float16)h_own;
            {
#pragma unroll
                for (int q = 0; q < 4; ++q) {
                    uint4 t4 = ((const uint4*)hbuf16)[q];
                    h2[4*q+0] = __builtin_bit_cast(v2h, t4.x);
                    h2[4*q+1] = __builtin_bit_cast(v2h, t4.y);
                    h2[4*q+2] = __builtin_bit_cast(v2h, t4.z);
                    h2[4*q+3] = __builtin_bit_cast(v2h, t4.w);
                }
                uint2 t2 = ((const uint2*)hbuf16)[8];
                h2[16] = __builtin_bit_cast(v2h, t2.x);
                h2[17] = __builtin_bit_cast(v2h, t2.y);
            }
        }
    }

    // head: out[b] = sum_j h[j] * w_head[j] + b_head
    float whead = (j < HH) ? w_head[j] : 0.f;
    float v = (j < HH) ? h_own * whead : 0.f;
#pragma unroll
    for (int off = 32; off; off >>= 1) v += __shfl_down(v, off);
    if (j == 0) out[b] = v + b_head[0];
}

extern "C" void kernel_launch(void* const* d_in, const int* in_sizes, int n_in,
                              void* d_out, int out_size, void* d_ws, size_t ws_size,
                              hipStream_t stream) {
    const float* x      = (const float*)d_in[0];
    const float* w_ih   = (const float*)d_in[1];
    const float* w_hh   = (const float*)d_in[2];
    const float* b_ih   = (const float*)d_in[3];
    const float* b_hh   = (const float*)d_in[4];
    const float* w_head = (const float*)d_in[5];
    const float* b_head = (const float*)d_in[6];
    float* out = (float*)d_out;

    gru_kernel<<<BB, 64, 0, stream>>>(x, w_ih, w_hh, b_ih, b_hh,
                                      w_head, b_head, out);
}